// Round 1
// baseline (881.613 us; speedup 1.0000x reference)
//
#include <hip/hip_runtime.h>

// out[b,h,i,j] = scores[b,h,i,j] + slope(h) * (j - (S-1))
// shape (2, 16, 2048, 2048) fp32.  slope(h) = 2^(-0.5*(h+1))
// Flat element index: idx = ((b*16 + h)*2048 + i)*2048 + j
//   j = idx & 2047          (row length 2048 = 2^11)
//   h = (idx >> 22) & 15    (2048*2048 = 2^22 elements per head-slice)
//
// R1: grid-stride form (Guideline 11). Previous version launched 131072
// workgroups doing 4 KB each — candidate WG-dispatch-overhead bound.
// 2048 blocks x 256 threads = 8 WG/CU, 64 float4 iterations per thread.

__global__ __launch_bounds__(256)
void alibi_add_kernel(const float4* __restrict__ in, float4* __restrict__ out,
                      long long n4) {
    const long long stride = (long long)gridDim.x * blockDim.x;      // 2^19 float4s
    const long long tid    = (long long)blockIdx.x * blockDim.x + threadIdx.x;

    // Column of this thread's first element is loop-invariant:
    // stride*4 elements = 2^21, a multiple of 2048, so (j) repeats every iter.
    // (Valid because grid/block are hard-coded below: stride % 512 == 0.)
    const float d0 = (float)((int)((tid * 4) & 2047) - 2047);

    #pragma unroll 4
    for (long long i4 = tid; i4 < n4; i4 += stride) {
        const int h = (int)((i4 >> 20) & 15);        // ((i4*4) >> 22) & 15
        const float slope = exp2f(-0.5f * (float)(h + 1));
        float4 v = in[i4];
        v.x += slope * d0;
        v.y += slope * (d0 + 1.0f);
        v.z += slope * (d0 + 2.0f);
        v.w += slope * (d0 + 3.0f);
        out[i4] = v;
    }
}

extern "C" void kernel_launch(void* const* d_in, const int* in_sizes, int n_in,
                              void* d_out, int out_size, void* d_ws, size_t ws_size,
                              hipStream_t stream) {
    const float4* in = (const float4*)d_in[0];
    float4* out = (float4*)d_out;

    const long long n4 = (long long)out_size / 4;    // 33554432 float4s
    const int block = 256;
    const int grid  = 2048;                          // 8 WG/CU, grid-stride (G11)

    alibi_add_kernel<<<grid, block, 0, stream>>>(in, out, n4);
}

// Round 2
// 806.755 us; speedup vs baseline: 1.0928x; 1.0928x over previous
//
#include <hip/hip_runtime.h>

// out[b,h,i,j] = scores[b,h,i,j] + slope(h) * (j - (S-1))
// shape (2, 16, 2048, 2048) fp32.  slope(h) = 2^(-0.5*(h+1))
// Flat layout: idx = ((b*16 + h)*2048 + i)*2048 + j
//   j = idx & 2047            (2048 = 2^11)
//   h = (idx >> 22) & 15      (2048*2048 = 2^22)
//
// R2: exact revert to R0 config (806 µs). R1's grid-stride (2048 blocks,
// 64 iters/thread) regressed +75 µs — the flat 1-float4/thread launch keeps
// the instantaneous footprint a dense contiguous front and measured
// ~123 µs kernel time (8.7 TB/s effective, LLC-assisted; above the 6.3 TB/s
// pure-HBM streaming ceiling). Do not "fix" the many-block launch: it wins.

__global__ __launch_bounds__(256)
void alibi_add_kernel(const float4* __restrict__ in, float4* __restrict__ out) {
    // one float4 (4 consecutive j) per thread; total/4 threads exactly
    const long long i4 = (long long)blockIdx.x * blockDim.x + threadIdx.x;
    const long long base = i4 * 4;                 // flat element index of .x

    const int j = (int)(base & 2047);              // column of first element
    const int h = (int)((base >> 22) & 15);        // head index

    const float slope = exp2f(-0.5f * (float)(h + 1));
    const float d0 = (float)(j - 2047);            // distance for .x

    float4 v = in[i4];
    v.x += slope * d0;
    v.y += slope * (d0 + 1.0f);
    v.z += slope * (d0 + 2.0f);
    v.w += slope * (d0 + 3.0f);
    out[i4] = v;
}

extern "C" void kernel_launch(void* const* d_in, const int* in_sizes, int n_in,
                              void* d_out, int out_size, void* d_ws, size_t ws_size,
                              hipStream_t stream) {
    const float4* in = (const float4*)d_in[0];
    float4* out = (float4*)d_out;

    const long long total = (long long)out_size;   // 2*16*2048*2048 = 134217728
    const long long n4 = total / 4;                // 33554432
    const int block = 256;
    const int grid = (int)(n4 / block);            // 131072, divides exactly

    alibi_add_kernel<<<grid, block, 0, stream>>>(in, out);
}